// Round 2
// baseline (498.811 us; speedup 1.0000x reference)
//
#include <hip/hip_runtime.h>
#include <math.h>

#define EMBED 1024
#define HEADS 16
#define HD    64
#define NB    4
#define LSEQ  2048

typedef __attribute__((ext_vector_type(8))) short bf16x8;
typedef __attribute__((ext_vector_type(16))) float f32x16;

typedef __attribute__((address_space(1))) void as1_void;
typedef __attribute__((address_space(3))) void as3_void;

__device__ __forceinline__ void gload_lds16(const void* g, void* l) {
    __builtin_amdgcn_global_load_lds((const as1_void*)g, (as3_void*)l, 16, 0, 0);
}

__device__ inline bf16x8 as_bf16x8(uint4 u) {
    union { uint4 u; bf16x8 b; } c; c.u = u; return c.b;
}
// round-to-nearest-even fp32 -> bf16 (raw ushort); finite inputs only
__device__ inline unsigned short bf16r(float x) {
    unsigned u = __float_as_uint(x);
    u += 0x7fffu + ((u >> 16) & 1u);
    return (unsigned short)(u >> 16);
}
__device__ inline float bfh2f(unsigned short h) {
    return __uint_as_float(((unsigned)h) << 16);
}
// split two floats into packed hi/lo bf16 words
__device__ inline void split2(float x, float y, unsigned& hw, unsigned& lw) {
    unsigned short hx = bf16r(x), hy = bf16r(y);
    unsigned short lx = bf16r(x - bfh2f(hx)), ly = bf16r(y - bfh2f(hy));
    hw = (unsigned)hx | ((unsigned)hy << 16);
    lw = (unsigned)lx | ((unsigned)ly << 16);
}

// ---------------------------------------------------------------------------
// Kernel 1: QKV projections as split-bf16 MFMA GEMM (unchanged from R6).
// ---------------------------------------------------------------------------
__global__ __launch_bounds__(256, 3) void proj_kernel(
    const float* __restrict__ Xv, const float* __restrict__ Xk, const float* __restrict__ Xq,
    const float* __restrict__ Wv, const float* __restrict__ Wk, const float* __restrict__ Wq,
    unsigned short* __restrict__ Vt, unsigned short* __restrict__ Kp, unsigned short* __restrict__ Qp)
{
    __shared__ uint4 sXh[128 * 8];   // [token][granule of 8 dims]  16KB
    __shared__ uint4 sXl[128 * 8];   // 16KB
    __shared__ uint4 sWh[64 * 8];    // [e][granule of 8 dims]       8KB
    __shared__ uint4 sWl[64 * 8];    //                              8KB

    const int t = threadIdx.x;
    const int lane = t & 63, w = t >> 6;
    const int l5 = lane & 31, hi = lane >> 5;
    const int h  = blockIdx.y;
    const int n  = blockIdx.x >> 4;
    const int l0 = (blockIdx.x & 15) * 128;

    const float QSC = 1.44269504088896341f / 32.0f;
    const float* Xs[3] = {Xv, Xk, Xq};
    const float* Ws[3] = {Wv, Wk, Wq};

    const int frow = t >> 4;        // staging: row group 0..15
    const int fcol = t & 15;        // float4 index within 64-dim row

    for (int p = 0; p < 3; ++p) {
        __syncthreads();
        // ---- stage X tile: 128 rows x 64 dims fp32 -> hi/lo bf16, swizzled ----
        {
            const float* xb = Xs[p] + ((size_t)(n * LSEQ + l0 + frow)) * EMBED + h * HD + fcol * 4;
            unsigned short* dh = (unsigned short*)sXh;
            unsigned short* dl = (unsigned short*)sXl;
            #pragma unroll
            for (int i = 0; i < 8; ++i) {
                int row = frow + i * 16;
                float4 v = *(const float4*)(xb + (size_t)i * 16 * EMBED);
                int gg = fcol >> 1, s8 = (fcol & 1) * 4;
                int idx = row * 64 + ((gg ^ (row & 7)) * 8) + s8;
                uint2 hv, lv;
                split2(v.x, v.y, hv.x, lv.x);
                split2(v.z, v.w, hv.y, lv.y);
                *(uint2*)(dh + idx) = hv;
                *(uint2*)(dl + idx) = lv;
            }
        }
        // ---- stage W: 64x64 fp32 -> hi/lo bf16, swizzled ----
        #pragma unroll
        for (int i = 0; i < 2; ++i) {
            int u = t + 256 * i;                  // granule 0..511
            int e = u >> 3, g = u & 7;
            const float* wb = Ws[p] + u * 8;
            float4 v0 = *(const float4*)(wb);
            float4 v1 = *(const float4*)(wb + 4);
            uint4 hq, lq;
            split2(v0.x, v0.y, hq.x, lq.x);
            split2(v0.z, v0.w, hq.y, lq.y);
            split2(v1.x, v1.y, hq.z, lq.z);
            split2(v1.z, v1.w, hq.w, lq.w);
            int idx = e * 8 + (g ^ (e & 7));
            sWh[idx] = hq;
            sWl[idx] = lq;
        }
        __syncthreads();

        // ---- MFMA: per wave, 32-token tile x (two 32-wide e-tiles) ----
        f32x16 acc0, acc1;
        #pragma unroll
        for (int i = 0; i < 16; ++i) { acc0[i] = 0.f; acc1[i] = 0.f; }

        const int xrow = w * 32 + l5;
        const int w0r = l5, w1r = 32 + l5;
        #pragma unroll
        for (int kc = 0; kc < 4; ++kc) {
            int gsel = kc * 2 + hi;
            bf16x8 xh = as_bf16x8(sXh[xrow * 8 + (gsel ^ (xrow & 7))]);
            bf16x8 xl = as_bf16x8(sXl[xrow * 8 + (gsel ^ (xrow & 7))]);
            bf16x8 wh0 = as_bf16x8(sWh[w0r * 8 + (gsel ^ (w0r & 7))]);
            bf16x8 wl0 = as_bf16x8(sWl[w0r * 8 + (gsel ^ (w0r & 7))]);
            bf16x8 wh1 = as_bf16x8(sWh[w1r * 8 + (gsel ^ (w1r & 7))]);
            bf16x8 wl1 = as_bf16x8(sWl[w1r * 8 + (gsel ^ (w1r & 7))]);
            if (p == 0) {
                // V^T = W X^T : A=W-frag (rows e), B=X-frag (cols token)
                acc0 = __builtin_amdgcn_mfma_f32_32x32x16_bf16(wh0, xh, acc0, 0, 0, 0);
                acc0 = __builtin_amdgcn_mfma_f32_32x32x16_bf16(wh0, xl, acc0, 0, 0, 0);
                acc0 = __builtin_amdgcn_mfma_f32_32x32x16_bf16(wl0, xh, acc0, 0, 0, 0);
                acc1 = __builtin_amdgcn_mfma_f32_32x32x16_bf16(wh1, xh, acc1, 0, 0, 0);
                acc1 = __builtin_amdgcn_mfma_f32_32x32x16_bf16(wh1, xl, acc1, 0, 0, 0);
                acc1 = __builtin_amdgcn_mfma_f32_32x32x16_bf16(wl1, xh, acc1, 0, 0, 0);
            } else {
                // C = X W^T : A=X-frag (rows token), B=W-frag (cols e)
                acc0 = __builtin_amdgcn_mfma_f32_32x32x16_bf16(xh, wh0, acc0, 0, 0, 0);
                acc0 = __builtin_amdgcn_mfma_f32_32x32x16_bf16(xh, wl0, acc0, 0, 0, 0);
                acc0 = __builtin_amdgcn_mfma_f32_32x32x16_bf16(xl, wh0, acc0, 0, 0, 0);
                acc1 = __builtin_amdgcn_mfma_f32_32x32x16_bf16(xh, wh1, acc1, 0, 0, 0);
                acc1 = __builtin_amdgcn_mfma_f32_32x32x16_bf16(xh, wl1, acc1, 0, 0, 0);
                acc1 = __builtin_amdgcn_mfma_f32_32x32x16_bf16(xl, wh1, acc1, 0, 0, 0);
            }
        }

        // ---- epilogue ----
        if (p == 0) {
            // C rows = e, cols = token (V^T): coalesced Vt [N,H,D,L] stores
            unsigned short* vb = Vt + (((size_t)(n * HEADS + h)) * HD) * LSEQ + l0 + w * 32 + l5;
            #pragma unroll
            for (int r = 0; r < 16; ++r) {
                int er = (r & 3) + 8 * (r >> 2) + 4 * hi;
                vb[(size_t)er * LSEQ]        = bf16r(acc0[r]);
                vb[(size_t)(32 + er) * LSEQ] = bf16r(acc1[r]);
            }
        } else {
            unsigned short* dst = (p == 1) ? Kp : Qp;
            float sc = (p == 2) ? QSC : 1.0f;
            unsigned short* db = dst + (((size_t)(n * HEADS + h)) * LSEQ + l0 + w * 32) * HD;
            #pragma unroll
            for (int r = 0; r < 16; ++r) {
                int tok = (r & 3) + 8 * (r >> 2) + 4 * hi;
                db[(size_t)tok * HD + l5]      = bf16r(acc0[r] * sc);
                db[(size_t)tok * HD + 32 + l5] = bf16r(acc1[r] * sc);
            }
        }
    }
}

// ---------------------------------------------------------------------------
// Kernel 2: MFMA flash attention, S^T orientation.
// R7 changes:
//  - T14 async-STAGE: next K/V tile prefetched into 32 VGPRs right after the
//    ds_writes of the current tile; the 8 global_load_dwordx4 stay in flight
//    across the barrier and land during the ~full compute phase, instead of
//    being serially exposed every K-tile (the structure was load->write->
//    barrier->compute with zero overlap).
//  - T5: s_setprio(1) around the QK^T and PV MFMA clusters (attn +4-7% in
//    isolated A/B, m191).
//  - lsum kept as fp32 adds (ones-row MFMA variant would cost 16 more AGPRs
//    and break the 128-reg budget needed for 4 blocks/CU), split into two
//    accumulators to shorten the dependency chain.
// ---------------------------------------------------------------------------
__global__ __launch_bounds__(256, 4) void attn_kernel(
    const unsigned short* __restrict__ Qp, const unsigned short* __restrict__ Kp,
    const unsigned short* __restrict__ Vt,
    unsigned short* __restrict__ AOh, unsigned short* __restrict__ AOl)
{
    __shared__ uint4 sK[128 * 8];    // 16KB
    __shared__ uint4 sV[64 * 16];    // 16KB

    const int t = threadIdx.x;
    const int lane = t & 63, w = t >> 6;
    const int l5 = lane & 31, hi = lane >> 5;
    const int n = blockIdx.z, h = blockIdx.y;
    const int q0 = blockIdx.x * 128;
    const size_t hoff = ((size_t)n * HEADS + h) * (size_t)(LSEQ * HD);
    const unsigned short* Kh = Kp + hoff;
    const unsigned short* Vh = Vt + hoff;

    bf16x8 qf[4];
    {
        const uint4* qg = (const uint4*)(Qp + hoff + (size_t)(q0 + w * 32 + l5) * HD);
        #pragma unroll
        for (int kc = 0; kc < 4; ++kc) qf[kc] = as_bf16x8(qg[kc * 2 + hi]);
    }

    f32x16 Oa0, Oa1;
    #pragma unroll
    for (int i = 0; i < 16; ++i) { Oa0[i] = 0.f; Oa1[i] = 0.f; }
    float ls0 = 0.f, ls1 = 0.f;

    // ---- T14 prologue: issue tile-0 loads into registers ----
    uint4 rK[4], rV[4];
    {
        const uint4* gK = (const uint4*)Kh;
        #pragma unroll
        for (int i = 0; i < 4; ++i) {
            int u = t + 256 * i;
            rK[i] = gK[u];
            int d = u >> 4, kg = u & 15;
            rV[i] = *(const uint4*)(Vh + (size_t)d * LSEQ + kg * 8);
        }
    }

    for (int kt = 0; kt < LSEQ; kt += 128) {
        // ---- write staged regs to LDS (swizzled) ----
        #pragma unroll
        for (int i = 0; i < 4; ++i) {
            int u = t + 256 * i;
            int key = u >> 3, gd = u & 7;
            sK[key * 8 + (gd ^ (key & 7))] = rK[i];
            int d = u >> 4, kg = u & 15;
            sV[d * 16 + (kg ^ (d & 7))] = rV[i];
        }
        // ---- issue next-tile loads; they complete during compute ----
        if (kt + 128 < LSEQ) {
            const uint4* gK = (const uint4*)(Kh + (size_t)(kt + 128) * HD);
            #pragma unroll
            for (int i = 0; i < 4; ++i) {
                int u = t + 256 * i;
                rK[i] = gK[u];
                int d = u >> 4, kg = u & 15;
                rV[i] = *(const uint4*)(Vh + (size_t)d * LSEQ + (kt + 128) + kg * 8);
            }
        }
        __syncthreads();

        #pragma unroll
        for (int tc = 0; tc < 4; ++tc) {
            f32x16 c;
            #pragma unroll
            for (int i = 0; i < 16; ++i) c[i] = 0.f;
            int key = tc * 32 + l5;
            __builtin_amdgcn_s_setprio(1);
            #pragma unroll
            for (int kc = 0; kc < 4; ++kc) {
                bf16x8 kf = as_bf16x8(sK[key * 8 + ((kc * 2 + hi) ^ (l5 & 7))]);
                c = __builtin_amdgcn_mfma_f32_32x32x16_bf16(kf, qf[kc], c, 0, 0, 0);
            }
            __builtin_amdgcn_s_setprio(0);

            // exp2 + pack adjacent key pairs to bf16 words, sum in fp32.
            // word (q,i) on lane hi holds keys (8q+4hi+2i, 8q+4hi+2i+1).
            unsigned pw[8];
            #pragma unroll
            for (int g = 0; g < 4; ++g) {
                float p0 = exp2f(c[4 * g]);
                float p1 = exp2f(c[4 * g + 1]);
                float p2 = exp2f(c[4 * g + 2]);
                float p3 = exp2f(c[4 * g + 3]);
                ls0 += (p0 + p1);
                ls1 += (p2 + p3);
                asm("v_cvt_pk_bf16_f32 %0, %1, %2" : "=v"(pw[2 * g])     : "v"(p0), "v"(p1));
                asm("v_cvt_pk_bf16_f32 %0, %1, %2" : "=v"(pw[2 * g + 1]) : "v"(p2), "v"(p3));
            }
            // cross-half exchange: swap lanes 32-63 of dst with 0-31 of src.
            asm("v_permlane32_swap_b32 %0, %1" : "+v"(pw[0]), "+v"(pw[2]));
            asm("v_permlane32_swap_b32 %0, %1" : "+v"(pw[1]), "+v"(pw[3]));
            asm("v_permlane32_swap_b32 %0, %1" : "+v"(pw[4]), "+v"(pw[6]));
            asm("v_permlane32_swap_b32 %0, %1" : "+v"(pw[5]), "+v"(pw[7]));

            __builtin_amdgcn_s_setprio(1);
            #pragma unroll
            for (int win = 0; win < 2; ++win) {
                union { unsigned u[4]; bf16x8 b; } pf;
                pf.u[0] = pw[4 * win];
                pf.u[1] = pw[4 * win + 1];
                pf.u[2] = pw[4 * win + 2];
                pf.u[3] = pw[4 * win + 3];
                int vg = tc * 4 + (win << 1) + hi;
                bf16x8 v0 = as_bf16x8(sV[ l5       * 16 + (vg ^ (l5 & 7))]);
                Oa0 = __builtin_amdgcn_mfma_f32_32x32x16_bf16(pf.b, v0, Oa0, 0, 0, 0);
                bf16x8 v1 = as_bf16x8(sV[(32 + l5) * 16 + (vg ^ (l5 & 7))]);
                Oa1 = __builtin_amdgcn_mfma_f32_32x32x16_bf16(pf.b, v1, Oa1, 0, 0, 0);
            }
            __builtin_amdgcn_s_setprio(0);
        }
        __syncthreads();
    }

    float lsum = ls0 + ls1;
    lsum += __shfl_xor(lsum, 32);
    float inv = 1.0f / lsum;
    float* sLf = (float*)sK;
    if (hi == 0) sLf[w * 32 + l5] = inv;

    unsigned short* hB = AOh + hoff;
    unsigned short* lB = AOl + hoff;
    #pragma unroll
    for (int r = 0; r < 16; ++r) {
        int qr = (r & 3) + 8 * (r >> 2) + 4 * hi;
        float invq = sLf[w * 32 + qr];
        size_t row = (size_t)(q0 + w * 32 + qr) * HD;
        float o0 = Oa0[r] * invq;
        float o1 = Oa1[r] * invq;
        unsigned short h0 = bf16r(o0), h1 = bf16r(o1);
        hB[row +      l5] = h0;
        hB[row + 32 + l5] = h1;
        lB[row +      l5] = bf16r(o0 - bfh2f(h0));
        lB[row + 32 + l5] = bf16r(o1 - bfh2f(h1));
    }
}

// ---------------------------------------------------------------------------
// Kernel 2.5: split Wo into bf16 hi/lo (unchanged).
// ---------------------------------------------------------------------------
__global__ __launch_bounds__(256) void wsplit_kernel(
    const float* __restrict__ Wo,
    unsigned short* __restrict__ Woh, unsigned short* __restrict__ Wol)
{
    int i = blockIdx.x * 256 + threadIdx.x;
    float4 v = ((const float4*)Wo)[i];
    ushort4 h, l;
    h.x = bf16r(v.x); l.x = bf16r(v.x - bfh2f(h.x));
    h.y = bf16r(v.y); l.y = bf16r(v.y - bfh2f(h.y));
    h.z = bf16r(v.z); l.z = bf16r(v.z - bfh2f(h.z));
    h.w = bf16r(v.w); l.w = bf16r(v.w - bfh2f(h.w));
    ((ushort4*)Woh)[i] = h;
    ((ushort4*)Wol)[i] = l;
}

// ---------------------------------------------------------------------------
// Kernel 3: output projection, split-bf16 MFMA GEMM (unchanged).
// ---------------------------------------------------------------------------
__global__ __launch_bounds__(256, 2) void outproj_kernel(
    const unsigned short* __restrict__ AOh, const unsigned short* __restrict__ AOl,
    const unsigned short* __restrict__ Woh, const unsigned short* __restrict__ Wol,
    const float* __restrict__ bo, float* __restrict__ out)
{
    __shared__ uint4 sAh[1024];
    __shared__ uint4 sAl[1024];
    __shared__ uint4 sBh[1024];
    __shared__ uint4 sBl[1024];

    const int t = threadIdx.x;
    const int lane = t & 63, w = t >> 6;
    const int l5 = lane & 31, hi = lane >> 5;
    const int m0 = blockIdx.x * 128;
    const int e0 = blockIdx.y * 128;
    const int n  = m0 >> 11, l0 = m0 & 2047;
    const int mr = (w & 1) * 64, nc = (w >> 1) * 64;

    f32x16 acc[2][2];
    #pragma unroll
    for (int a = 0; a < 2; ++a)
        #pragma unroll
        for (int b = 0; b < 2; ++b)
            #pragma unroll
            for (int i = 0; i < 16; ++i) acc[a][b][i] = 0.f;

    for (int hh = 0; hh < 16; ++hh) {
        const unsigned short* Ah = AOh + ((((size_t)n * HEADS + hh) * LSEQ) + l0) * HD;
        const unsigned short* Al = AOl + ((((size_t)n * HEADS + hh) * LSEQ) + l0) * HD;
        #pragma unroll
        for (int i = 0; i < 4; ++i) {
            int g = t + i * 256;
            gload_lds16(Ah + g * 8, sAh + g);
            gload_lds16(Al + g * 8, sAl + g);
            int e = g >> 3, gf = g & 7;
            size_t boff = (size_t)(e0 + e) * EMBED + hh * 64 + gf * 8;
            gload_lds16(Woh + boff, sBh + g);
            gload_lds16(Wol + boff, sBl + g);
        }
        __syncthreads();

        #pragma unroll
        for (int s = 0; s < 4; ++s) {
            int gcol = s * 2 + hi;
            bf16x8 ah0 = as_bf16x8(sAh[(mr +      l5) * 8 + gcol]);
            bf16x8 ah1 = as_bf16x8(sAh[(mr + 32 + l5) * 8 + gcol]);
            bf16x8 al0 = as_bf16x8(sAl[(mr +      l5) * 8 + gcol]);
            bf16x8 al1 = as_bf16x8(sAl[(mr + 32 + l5) * 8 + gcol]);
            bf16x8 bh0 = as_bf16x8(sBh[(nc +      l5) * 8 + gcol]);
            bf16x8 bh1 = as_bf16x8(sBh[(nc + 32 + l5) * 8 + gcol]);
            bf16x8 bl0 = as_bf16x8(sBl[(nc +      l5) * 8 + gcol]);
            bf16x8 bl1 = as_bf16x8(sBl[(nc + 32 + l5) * 8 + gcol]);

            acc[0][0] = __builtin_amdgcn_mfma_f32_32x32x16_bf16(ah0, bh0, acc[0][0], 0, 0, 0);
            acc[0][1] = __builtin_amdgcn_mfma_f32_32x32x16_bf16(ah0, bh1, acc[0][1], 0, 0, 0);
            acc[1][0] = __builtin_amdgcn_mfma_f32_32x32x16_bf16(ah1, bh0, acc[1][0], 0, 0, 0);
            acc[1][1] = __builtin_amdgcn_mfma_f32_32x32x16_bf16(ah1, bh1, acc[1][1], 0, 0, 0);

            acc[0][0] = __builtin_amdgcn_mfma_f32_32x32x16_bf16(ah0, bl0, acc[0][0], 0, 0, 0);
            acc[0][1] = __builtin_amdgcn_mfma_f32_32x32x16_bf16(ah0, bl1, acc[0][1], 0, 0, 0);
            acc[1][0] = __builtin_amdgcn_mfma_f32_32x32x16_bf16(ah1, bl0, acc[1][0], 0, 0, 0);
            acc[1][1] = __builtin_amdgcn_mfma_f32_32x32x16_bf16(ah1, bl1, acc[1][1], 0, 0, 0);

            acc[0][0] = __builtin_amdgcn_mfma_f32_32x32x16_bf16(al0, bh0, acc[0][0], 0, 0, 0);
            acc[0][1] = __builtin_amdgcn_mfma_f32_32x32x16_bf16(al0, bh1, acc[0][1], 0, 0, 0);
            acc[1][0] = __builtin_amdgcn_mfma_f32_32x32x16_bf16(al1, bh0, acc[1][0], 0, 0, 0);
            acc[1][1] = __builtin_amdgcn_mfma_f32_32x32x16_bf16(al1, bh1, acc[1][1], 0, 0, 0);
        }
        __syncthreads();
    }

    float b0 = bo[e0 + nc + l5];
    float b1 = bo[e0 + nc + 32 + l5];
    #pragma unroll
    for (int ti = 0; ti < 2; ++ti) {
        #pragma unroll
        for (int r = 0; r < 16; ++r) {
            int row = m0 + mr + ti * 32 + (r & 3) + 8 * (r >> 2) + 4 * hi;
            float* o = out + (size_t)row * EMBED + e0 + nc;
            o[l5]      = acc[ti][0][r] + b0;
            o[32 + l5] = acc[ti][1][r] + b1;
        }
    }
}

// ---------------------------------------------------------------------------
extern "C" void kernel_launch(void* const* d_in, const int* in_sizes, int n_in,
                              void* d_out, int out_size, void* d_ws, size_t ws_size,
                              hipStream_t stream)
{
    const float* values  = (const float*)d_in[0];
    const float* keys    = (const float*)d_in[1];
    const float* queries = (const float*)d_in[2];
    const float* Wv      = (const float*)d_in[3];
    const float* Wk      = (const float*)d_in[4];
    const float* Wq      = (const float*)d_in[5];
    const float* Wo      = (const float*)d_in[6];
    const float* bo      = (const float*)d_in[7];
    float* out = (float*)d_out;

    const size_t bufElems = (size_t)NB * HEADS * LSEQ * HD;   // 8,388,608
    unsigned short* Qp  = (unsigned short*)d_ws;
    unsigned short* Kp  = Qp  + bufElems;
    unsigned short* Vt  = Kp  + bufElems;
    unsigned short* AOh = Vt  + bufElems;
    unsigned short* AOl = AOh + bufElems;
    unsigned short* Woh = AOl + bufElems;
    unsigned short* Wol = Woh + (size_t)EMBED * EMBED;

    wsplit_kernel<<<dim3(1024), 256, 0, stream>>>(Wo, Woh, Wol);
    proj_kernel<<<dim3(NB * 16, HEADS), 256, 0, stream>>>(values, keys, queries, Wv, Wk, Wq, Vt, Kp, Qp);
    attn_kernel<<<dim3(LSEQ / 128, HEADS, NB), 256, 0, stream>>>(Qp, Kp, Vt, AOh, AOl);
    outproj_kernel<<<dim3(NB * LSEQ / 128, EMBED / 128), 256, 0, stream>>>(AOh, AOl, Woh, Wol, bo, out);
}

// Round 3
// 377.927 us; speedup vs baseline: 1.3199x; 1.3199x over previous
//
#include <hip/hip_runtime.h>
#include <math.h>

#define EMBED 1024
#define HEADS 16
#define HD    64
#define NB    4
#define LSEQ  2048

typedef __attribute__((ext_vector_type(8))) short bf16x8;
typedef __attribute__((ext_vector_type(16))) float f32x16;

typedef __attribute__((address_space(1))) void as1_void;
typedef __attribute__((address_space(3))) void as3_void;

__device__ __forceinline__ void gload_lds16(const void* g, void* l) {
    __builtin_amdgcn_global_load_lds((const as1_void*)g, (as3_void*)l, 16, 0, 0);
}

__device__ inline bf16x8 as_bf16x8(uint4 u) {
    union { uint4 u; bf16x8 b; } c; c.u = u; return c.b;
}
// round-to-nearest-even fp32 -> bf16 (raw ushort); finite inputs only
__device__ inline unsigned short bf16r(float x) {
    unsigned u = __float_as_uint(x);
    u += 0x7fffu + ((u >> 16) & 1u);
    return (unsigned short)(u >> 16);
}
__device__ inline float bfh2f(unsigned short h) {
    return __uint_as_float(((unsigned)h) << 16);
}
// split two floats into packed hi/lo bf16 words
__device__ inline void split2(float x, float y, unsigned& hw, unsigned& lw) {
    unsigned short hx = bf16r(x), hy = bf16r(y);
    unsigned short lx = bf16r(x - bfh2f(hx)), ly = bf16r(y - bfh2f(hy));
    hw = (unsigned)hx | ((unsigned)hy << 16);
    lw = (unsigned)lx | ((unsigned)ly << 16);
}

// ---------------------------------------------------------------------------
// Kernel 1: QKV projections as split-bf16 MFMA GEMM (unchanged from R6).
// ---------------------------------------------------------------------------
__global__ __launch_bounds__(256, 3) void proj_kernel(
    const float* __restrict__ Xv, const float* __restrict__ Xk, const float* __restrict__ Xq,
    const float* __restrict__ Wv, const float* __restrict__ Wk, const float* __restrict__ Wq,
    unsigned short* __restrict__ Vt, unsigned short* __restrict__ Kp, unsigned short* __restrict__ Qp)
{
    __shared__ uint4 sXh[128 * 8];   // [token][granule of 8 dims]  16KB
    __shared__ uint4 sXl[128 * 8];   // 16KB
    __shared__ uint4 sWh[64 * 8];    // [e][granule of 8 dims]       8KB
    __shared__ uint4 sWl[64 * 8];    //                              8KB

    const int t = threadIdx.x;
    const int lane = t & 63, w = t >> 6;
    const int l5 = lane & 31, hi = lane >> 5;
    const int h  = blockIdx.y;
    const int n  = blockIdx.x >> 4;
    const int l0 = (blockIdx.x & 15) * 128;

    const float QSC = 1.44269504088896341f / 32.0f;
    const float* Xs[3] = {Xv, Xk, Xq};
    const float* Ws[3] = {Wv, Wk, Wq};

    const int frow = t >> 4;        // staging: row group 0..15
    const int fcol = t & 15;        // float4 index within 64-dim row

    for (int p = 0; p < 3; ++p) {
        __syncthreads();
        // ---- stage X tile: 128 rows x 64 dims fp32 -> hi/lo bf16, swizzled ----
        {
            const float* xb = Xs[p] + ((size_t)(n * LSEQ + l0 + frow)) * EMBED + h * HD + fcol * 4;
            unsigned short* dh = (unsigned short*)sXh;
            unsigned short* dl = (unsigned short*)sXl;
            #pragma unroll
            for (int i = 0; i < 8; ++i) {
                int row = frow + i * 16;
                float4 v = *(const float4*)(xb + (size_t)i * 16 * EMBED);
                int gg = fcol >> 1, s8 = (fcol & 1) * 4;
                int idx = row * 64 + ((gg ^ (row & 7)) * 8) + s8;
                uint2 hv, lv;
                split2(v.x, v.y, hv.x, lv.x);
                split2(v.z, v.w, hv.y, lv.y);
                *(uint2*)(dh + idx) = hv;
                *(uint2*)(dl + idx) = lv;
            }
        }
        // ---- stage W: 64x64 fp32 -> hi/lo bf16, swizzled ----
        #pragma unroll
        for (int i = 0; i < 2; ++i) {
            int u = t + 256 * i;                  // granule 0..511
            int e = u >> 3, g = u & 7;
            const float* wb = Ws[p] + u * 8;
            float4 v0 = *(const float4*)(wb);
            float4 v1 = *(const float4*)(wb + 4);
            uint4 hq, lq;
            split2(v0.x, v0.y, hq.x, lq.x);
            split2(v0.z, v0.w, hq.y, lq.y);
            split2(v1.x, v1.y, hq.z, lq.z);
            split2(v1.z, v1.w, hq.w, lq.w);
            int idx = e * 8 + (g ^ (e & 7));
            sWh[idx] = hq;
            sWl[idx] = lq;
        }
        __syncthreads();

        // ---- MFMA: per wave, 32-token tile x (two 32-wide e-tiles) ----
        f32x16 acc0, acc1;
        #pragma unroll
        for (int i = 0; i < 16; ++i) { acc0[i] = 0.f; acc1[i] = 0.f; }

        const int xrow = w * 32 + l5;
        const int w0r = l5, w1r = 32 + l5;
        #pragma unroll
        for (int kc = 0; kc < 4; ++kc) {
            int gsel = kc * 2 + hi;
            bf16x8 xh = as_bf16x8(sXh[xrow * 8 + (gsel ^ (xrow & 7))]);
            bf16x8 xl = as_bf16x8(sXl[xrow * 8 + (gsel ^ (xrow & 7))]);
            bf16x8 wh0 = as_bf16x8(sWh[w0r * 8 + (gsel ^ (w0r & 7))]);
            bf16x8 wl0 = as_bf16x8(sWl[w0r * 8 + (gsel ^ (w0r & 7))]);
            bf16x8 wh1 = as_bf16x8(sWh[w1r * 8 + (gsel ^ (w1r & 7))]);
            bf16x8 wl1 = as_bf16x8(sWl[w1r * 8 + (gsel ^ (w1r & 7))]);
            if (p == 0) {
                // V^T = W X^T : A=W-frag (rows e), B=X-frag (cols token)
                acc0 = __builtin_amdgcn_mfma_f32_32x32x16_bf16(wh0, xh, acc0, 0, 0, 0);
                acc0 = __builtin_amdgcn_mfma_f32_32x32x16_bf16(wh0, xl, acc0, 0, 0, 0);
                acc0 = __builtin_amdgcn_mfma_f32_32x32x16_bf16(wl0, xh, acc0, 0, 0, 0);
                acc1 = __builtin_amdgcn_mfma_f32_32x32x16_bf16(wh1, xh, acc1, 0, 0, 0);
                acc1 = __builtin_amdgcn_mfma_f32_32x32x16_bf16(wh1, xl, acc1, 0, 0, 0);
                acc1 = __builtin_amdgcn_mfma_f32_32x32x16_bf16(wl1, xh, acc1, 0, 0, 0);
            } else {
                // C = X W^T : A=X-frag (rows token), B=W-frag (cols e)
                acc0 = __builtin_amdgcn_mfma_f32_32x32x16_bf16(xh, wh0, acc0, 0, 0, 0);
                acc0 = __builtin_amdgcn_mfma_f32_32x32x16_bf16(xh, wl0, acc0, 0, 0, 0);
                acc0 = __builtin_amdgcn_mfma_f32_32x32x16_bf16(xl, wh0, acc0, 0, 0, 0);
                acc1 = __builtin_amdgcn_mfma_f32_32x32x16_bf16(xh, wh1, acc1, 0, 0, 0);
                acc1 = __builtin_amdgcn_mfma_f32_32x32x16_bf16(xh, wl1, acc1, 0, 0, 0);
                acc1 = __builtin_amdgcn_mfma_f32_32x32x16_bf16(xl, wh1, acc1, 0, 0, 0);
            }
        }

        // ---- epilogue ----
        if (p == 0) {
            // C rows = e, cols = token (V^T): coalesced Vt [N,H,D,L] stores
            unsigned short* vb = Vt + (((size_t)(n * HEADS + h)) * HD) * LSEQ + l0 + w * 32 + l5;
            #pragma unroll
            for (int r = 0; r < 16; ++r) {
                int er = (r & 3) + 8 * (r >> 2) + 4 * hi;
                vb[(size_t)er * LSEQ]        = bf16r(acc0[r]);
                vb[(size_t)(32 + er) * LSEQ] = bf16r(acc1[r]);
            }
        } else {
            unsigned short* dst = (p == 1) ? Kp : Qp;
            float sc = (p == 2) ? QSC : 1.0f;
            unsigned short* db = dst + (((size_t)(n * HEADS + h)) * LSEQ + l0 + w * 32) * HD;
            #pragma unroll
            for (int r = 0; r < 16; ++r) {
                int tok = (r & 3) + 8 * (r >> 2) + 4 * hi;
                db[(size_t)tok * HD + l5]      = bf16r(acc0[r] * sc);
                db[(size_t)tok * HD + 32 + l5] = bf16r(acc1[r] * sc);
            }
        }
    }
}

// ---------------------------------------------------------------------------
// Kernel 2: MFMA flash attention, S^T orientation.
// R8 changes (after R7's register-prefetch spilled to scratch: WRITE_SIZE
// 32->573MB, dur 130->232us):
//  - KVBLK 128 -> 64; K/V double-buffered in LDS (8+8KB per buffer, 32KB
//    total -> still 4 blocks/CU).
//  - Staging via global_load_lds (no VGPR round-trip, zero register cost).
//    LDS dest is linear (DMA requirement); the XOR swizzle is applied to the
//    per-lane GLOBAL source address instead (both-sides-or-neither, m173).
//    Source permutation stays within 128B rows -> still fully coalesced.
//  - Counted vmcnt: next tile's 4 loads are issued before the barrier and
//    stay in flight across it (s_waitcnt vmcnt(4), never 0 in the loop),
//    raw s_barrier (no compiler vmcnt(0) drain).
//  - T5 setprio around MFMA clusters kept.
// ---------------------------------------------------------------------------
__global__ __launch_bounds__(256, 4) void attn_kernel(
    const unsigned short* __restrict__ Qp, const unsigned short* __restrict__ Kp,
    const unsigned short* __restrict__ Vt,
    unsigned short* __restrict__ AOh, unsigned short* __restrict__ AOl)
{
    __shared__ uint4 sK[2][64 * 8];  // [buf][key][granule]  8KB each
    __shared__ uint4 sV[2][64 * 8];  // [buf][d][key-granule] 8KB each

    const int t = threadIdx.x;
    const int lane = t & 63, w = t >> 6;
    const int l5 = lane & 31, hi = lane >> 5;
    const int n = blockIdx.z, h = blockIdx.y;
    const int q0 = blockIdx.x * 128;
    const size_t hoff = ((size_t)n * HEADS + h) * (size_t)(LSEQ * HD);
    const unsigned short* Kh = Kp + hoff;
    const unsigned short* Vh = Vt + hoff;

    bf16x8 qf[4];
    {
        const uint4* qg = (const uint4*)(Qp + hoff + (size_t)(q0 + w * 32 + l5) * HD);
        #pragma unroll
        for (int kc = 0; kc < 4; ++kc) qf[kc] = as_bf16x8(qg[kc * 2 + hi]);
    }

    f32x16 Oa0, Oa1;
    #pragma unroll
    for (int i = 0; i < 16; ++i) { Oa0[i] = 0.f; Oa1[i] = 0.f; }
    float ls0 = 0.f, ls1 = 0.f;

    // pre-swizzled source constants: LDS slot idx holds global granule
    // ((idx>>3), (idx&7)^((idx>>3)&7)); rows for slots t and t+256 differ by
    // 32 so the XOR term is identical.
    const int r0 = t >> 3;                       // key-row / d-row 0..31
    const int g0 = (t & 7) ^ (r0 & 7);           // swizzled granule
    const uint4* gK = (const uint4*)Kh;
    const uint4* gV = (const uint4*)Vh;          // V^T: 256 uint4 per d-row

    #define STAGE(TILE, BUF)                                                        \
        do {                                                                        \
            int kb_ = (TILE) * 64;                                                  \
            gload_lds16(gK + (size_t)(kb_ + r0) * 8 + g0,        &sK[BUF][t]);      \
            gload_lds16(gK + (size_t)(kb_ + r0 + 32) * 8 + g0,   &sK[BUF][t + 256]);\
            gload_lds16(gV + (size_t)r0 * 256 + (kb_ >> 3) + g0, &sV[BUF][t]);      \
            gload_lds16(gV + (size_t)(r0 + 32) * 256 + (kb_ >> 3) + g0,             \
                        &sV[BUF][t + 256]);                                         \
        } while (0)

    STAGE(0, 0);
    int cur = 0;

    for (int tt = 0; tt < LSEQ / 64; ++tt) {
        if (tt + 1 < LSEQ / 64) {
            STAGE(tt + 1, cur ^ 1);
            asm volatile("s_waitcnt vmcnt(4)" ::: "memory");
        } else {
            asm volatile("s_waitcnt vmcnt(0)" ::: "memory");
        }
        __builtin_amdgcn_s_barrier();

        #pragma unroll
        for (int tc = 0; tc < 2; ++tc) {
            f32x16 c;
            #pragma unroll
            for (int i = 0; i < 16; ++i) c[i] = 0.f;
            int key = tc * 32 + l5;
            __builtin_amdgcn_s_setprio(1);
            #pragma unroll
            for (int kc = 0; kc < 4; ++kc) {
                bf16x8 kf = as_bf16x8(sK[cur][key * 8 + ((kc * 2 + hi) ^ (l5 & 7))]);
                c = __builtin_amdgcn_mfma_f32_32x32x16_bf16(kf, qf[kc], c, 0, 0, 0);
            }
            __builtin_amdgcn_s_setprio(0);

            // exp2 + pack adjacent key pairs to bf16 words, sum in fp32.
            unsigned pw[8];
            #pragma unroll
            for (int g = 0; g < 4; ++g) {
                float p0 = exp2f(c[4 * g]);
                float p1 = exp2f(c[4 * g + 1]);
                float p2 = exp2f(c[4 * g + 2]);
                float p3 = exp2f(c[4 * g + 3]);
                ls0 += (p0 + p1);
                ls1 += (p2 + p3);
                asm("v_cvt_pk_bf16_f32 %0, %1, %2" : "=v"(pw[2 * g])     : "v"(p0), "v"(p1));
                asm("v_cvt_pk_bf16_f32 %0, %1, %2" : "=v"(pw[2 * g + 1]) : "v"(p2), "v"(p3));
            }
            // cross-half exchange: swap lanes 32-63 of dst with 0-31 of src.
            asm("v_permlane32_swap_b32 %0, %1" : "+v"(pw[0]), "+v"(pw[2]));
            asm("v_permlane32_swap_b32 %0, %1" : "+v"(pw[1]), "+v"(pw[3]));
            asm("v_permlane32_swap_b32 %0, %1" : "+v"(pw[4]), "+v"(pw[6]));
            asm("v_permlane32_swap_b32 %0, %1" : "+v"(pw[5]), "+v"(pw[7]));

            __builtin_amdgcn_s_setprio(1);
            #pragma unroll
            for (int win = 0; win < 2; ++win) {
                union { unsigned u[4]; bf16x8 b; } pf;
                pf.u[0] = pw[4 * win];
                pf.u[1] = pw[4 * win + 1];
                pf.u[2] = pw[4 * win + 2];
                pf.u[3] = pw[4 * win + 3];
                int vg = tc * 4 + (win << 1) + hi;
                bf16x8 v0 = as_bf16x8(sV[cur][ l5       * 8 + (vg ^ (l5 & 7))]);
                Oa0 = __builtin_amdgcn_mfma_f32_32x32x16_bf16(pf.b, v0, Oa0, 0, 0, 0);
                bf16x8 v1 = as_bf16x8(sV[cur][(32 + l5) * 8 + (vg ^ (l5 & 7))]);
                Oa1 = __builtin_amdgcn_mfma_f32_32x32x16_bf16(pf.b, v1, Oa1, 0, 0, 0);
            }
            __builtin_amdgcn_s_setprio(0);
        }
        __builtin_amdgcn_s_barrier();
        cur ^= 1;
    }
    #undef STAGE

    float lsum = ls0 + ls1;
    lsum += __shfl_xor(lsum, 32);
    float inv = 1.0f / lsum;
    float* sLf = (float*)&sK[0][0];
    if (hi == 0) sLf[w * 32 + l5] = inv;
    __syncthreads();

    unsigned short* hB = AOh + hoff;
    unsigned short* lB = AOl + hoff;
    #pragma unroll
    for (int r = 0; r < 16; ++r) {
        int qr = (r & 3) + 8 * (r >> 2) + 4 * hi;
        float invq = sLf[w * 32 + qr];
        size_t row = (size_t)(q0 + w * 32 + qr) * HD;
        float o0 = Oa0[r] * invq;
        float o1 = Oa1[r] * invq;
        unsigned short h0 = bf16r(o0), h1 = bf16r(o1);
        hB[row +      l5] = h0;
        hB[row + 32 + l5] = h1;
        lB[row +      l5] = bf16r(o0 - bfh2f(h0));
        lB[row + 32 + l5] = bf16r(o1 - bfh2f(h1));
    }
}

// ---------------------------------------------------------------------------
// Kernel 2.5: split Wo into bf16 hi/lo (unchanged).
// ---------------------------------------------------------------------------
__global__ __launch_bounds__(256) void wsplit_kernel(
    const float* __restrict__ Wo,
    unsigned short* __restrict__ Woh, unsigned short* __restrict__ Wol)
{
    int i = blockIdx.x * 256 + threadIdx.x;
    float4 v = ((const float4*)Wo)[i];
    ushort4 h, l;
    h.x = bf16r(v.x); l.x = bf16r(v.x - bfh2f(h.x));
    h.y = bf16r(v.y); l.y = bf16r(v.y - bfh2f(h.y));
    h.z = bf16r(v.z); l.z = bf16r(v.z - bfh2f(h.z));
    h.w = bf16r(v.w); l.w = bf16r(v.w - bfh2f(h.w));
    ((ushort4*)Woh)[i] = h;
    ((ushort4*)Wol)[i] = l;
}

// ---------------------------------------------------------------------------
// Kernel 3: output projection, split-bf16 MFMA GEMM (unchanged).
// ---------------------------------------------------------------------------
__global__ __launch_bounds__(256, 2) void outproj_kernel(
    const unsigned short* __restrict__ AOh, const unsigned short* __restrict__ AOl,
    const unsigned short* __restrict__ Woh, const unsigned short* __restrict__ Wol,
    const float* __restrict__ bo, float* __restrict__ out)
{
    __shared__ uint4 sAh[1024];
    __shared__ uint4 sAl[1024];
    __shared__ uint4 sBh[1024];
    __shared__ uint4 sBl[1024];

    const int t = threadIdx.x;
    const int lane = t & 63, w = t >> 6;
    const int l5 = lane & 31, hi = lane >> 5;
    const int m0 = blockIdx.x * 128;
    const int e0 = blockIdx.y * 128;
    const int n  = m0 >> 11, l0 = m0 & 2047;
    const int mr = (w & 1) * 64, nc = (w >> 1) * 64;

    f32x16 acc[2][2];
    #pragma unroll
    for (int a = 0; a < 2; ++a)
        #pragma unroll
        for (int b = 0; b < 2; ++b)
            #pragma unroll
            for (int i = 0; i < 16; ++i) acc[a][b][i] = 0.f;

    for (int hh = 0; hh < 16; ++hh) {
        const unsigned short* Ah = AOh + ((((size_t)n * HEADS + hh) * LSEQ) + l0) * HD;
        const unsigned short* Al = AOl + ((((size_t)n * HEADS + hh) * LSEQ) + l0) * HD;
        #pragma unroll
        for (int i = 0; i < 4; ++i) {
            int g = t + i * 256;
            gload_lds16(Ah + g * 8, sAh + g);
            gload_lds16(Al + g * 8, sAl + g);
            int e = g >> 3, gf = g & 7;
            size_t boff = (size_t)(e0 + e) * EMBED + hh * 64 + gf * 8;
            gload_lds16(Woh + boff, sBh + g);
            gload_lds16(Wol + boff, sBl + g);
        }
        __syncthreads();

        #pragma unroll
        for (int s = 0; s < 4; ++s) {
            int gcol = s * 2 + hi;
            bf16x8 ah0 = as_bf16x8(sAh[(mr +      l5) * 8 + gcol]);
            bf16x8 ah1 = as_bf16x8(sAh[(mr + 32 + l5) * 8 + gcol]);
            bf16x8 al0 = as_bf16x8(sAl[(mr +      l5) * 8 + gcol]);
            bf16x8 al1 = as_bf16x8(sAl[(mr + 32 + l5) * 8 + gcol]);
            bf16x8 bh0 = as_bf16x8(sBh[(nc +      l5) * 8 + gcol]);
            bf16x8 bh1 = as_bf16x8(sBh[(nc + 32 + l5) * 8 + gcol]);
            bf16x8 bl0 = as_bf16x8(sBl[(nc +      l5) * 8 + gcol]);
            bf16x8 bl1 = as_bf16x8(sBl[(nc + 32 + l5) * 8 + gcol]);

            acc[0][0] = __builtin_amdgcn_mfma_f32_32x32x16_bf16(ah0, bh0, acc[0][0], 0, 0, 0);
            acc[0][1] = __builtin_amdgcn_mfma_f32_32x32x16_bf16(ah0, bh1, acc[0][1], 0, 0, 0);
            acc[1][0] = __builtin_amdgcn_mfma_f32_32x32x16_bf16(ah1, bh0, acc[1][0], 0, 0, 0);
            acc[1][1] = __builtin_amdgcn_mfma_f32_32x32x16_bf16(ah1, bh1, acc[1][1], 0, 0, 0);

            acc[0][0] = __builtin_amdgcn_mfma_f32_32x32x16_bf16(ah0, bl0, acc[0][0], 0, 0, 0);
            acc[0][1] = __builtin_amdgcn_mfma_f32_32x32x16_bf16(ah0, bl1, acc[0][1], 0, 0, 0);
            acc[1][0] = __builtin_amdgcn_mfma_f32_32x32x16_bf16(ah1, bl0, acc[1][0], 0, 0, 0);
            acc[1][1] = __builtin_amdgcn_mfma_f32_32x32x16_bf16(ah1, bl1, acc[1][1], 0, 0, 0);

            acc[0][0] = __builtin_amdgcn_mfma_f32_32x32x16_bf16(al0, bh0, acc[0][0], 0, 0, 0);
            acc[0][1] = __builtin_amdgcn_mfma_f32_32x32x16_bf16(al0, bh1, acc[0][1], 0, 0, 0);
            acc[1][0] = __builtin_amdgcn_mfma_f32_32x32x16_bf16(al1, bh0, acc[1][0], 0, 0, 0);
            acc[1][1] = __builtin_amdgcn_mfma_f32_32x32x16_bf16(al1, bh1, acc[1][1], 0, 0, 0);
        }
        __syncthreads();
    }

    float b0 = bo[e0 + nc + l5];
    float b1 = bo[e0 + nc + 32 + l5];
    #pragma unroll
    for (int ti = 0; ti < 2; ++ti) {
        #pragma unroll
        for (int r = 0; r < 16; ++r) {
            int row = m0 + mr + ti * 32 + (r & 3) + 8 * (r >> 2) + 4 * hi;
            float* o = out + (size_t)row * EMBED + e0 + nc;
            o[l5]      = acc[ti][0][r] + b0;
            o[32 + l5] = acc[ti][1][r] + b1;
        }
    }
}

// ---------------------------------------------------------------------------
extern "C" void kernel_launch(void* const* d_in, const int* in_sizes, int n_in,
                              void* d_out, int out_size, void* d_ws, size_t ws_size,
                              hipStream_t stream)
{
    const float* values  = (const float*)d_in[0];
    const float* keys    = (const float*)d_in[1];
    const float* queries = (const float*)d_in[2];
    const float* Wv      = (const float*)d_in[3];
    const float* Wk      = (const float*)d_in[4];
    const float* Wq      = (const float*)d_in[5];
    const float* Wo      = (const float*)d_in[6];
    const float* bo      = (const float*)d_in[7];
    float* out = (float*)d_out;

    const size_t bufElems = (size_t)NB * HEADS * LSEQ * HD;   // 8,388,608
    unsigned short* Qp  = (unsigned short*)d_ws;
    unsigned short* Kp  = Qp  + bufElems;
    unsigned short* Vt  = Kp  + bufElems;
    unsigned short* AOh = Vt  + bufElems;
    unsigned short* AOl = AOh + bufElems;
    unsigned short* Woh = AOl + bufElems;
    unsigned short* Wol = Woh + (size_t)EMBED * EMBED;

    wsplit_kernel<<<dim3(1024), 256, 0, stream>>>(Wo, Woh, Wol);
    proj_kernel<<<dim3(NB * 16, HEADS), 256, 0, stream>>>(values, keys, queries, Wv, Wk, Wq, Vt, Kp, Qp);
    attn_kernel<<<dim3(LSEQ / 128, HEADS, NB), 256, 0, stream>>>(Qp, Kp, Vt, AOh, AOl);
    outproj_kernel<<<dim3(NB * LSEQ / 128, EMBED / 128), 256, 0, stream>>>(AOh, AOl, Woh, Wol, bo, out);
}